// Round 20
// baseline (2170.511 us; speedup 1.0000x reference)
//
#include <hip/hip_runtime.h>
#include <hip/hip_bf16.h>
#include <math.h>

// ---------------- problem constants ----------------
#define NGRP 16     // batch groups (one per batch element)
#define GWG  8      // workgroups per group (= heads)
#define NBLK (NGRP*GWG)   // 128
#define NTHR 512
#define TSEQ 48
#define DDIM 256
#define HDIM 32
#define NLAY 3
#define NOUT 6

// ---------------- ws layout ----------------
#define CNT_OFF   0u
#define CNT_BYTES 16384u         // 16 groups x 8 flag slots x 128B
#define GRP_OFF   16384u
#define GRP_STRF  5120u          // floats per group block
#define PO_F   0                 // [8*256] oproj partials
#define PF_F   2048              // [8*256] ff2 partials
#define CAL_F  4096              // [3*256] cross-attn constants
#define WB_OFF 360448u           // bf16 weights (element offsets below)
#define WOFF_QKV 0u
#define WOFF_WO  589824u
#define WOFF_F1  786432u
#define WOFF_F2  1572864u
#define WOFF_OP1 2359296u
#define NCVT     2392064u

typedef __attribute__((address_space(1))) const unsigned int gu32;
typedef __attribute__((address_space(3))) unsigned int lu32;

__device__ __forceinline__ void gl_lds16(const unsigned short* g, unsigned short* l) {
  __builtin_amdgcn_global_load_lds((gu32*)g, (lu32*)l, 16, 0, 0);
}
__device__ __forceinline__ void bfp(unsigned int u, float& lo, float& hi) {
  union { unsigned int i; float f; } a, b;
  a.i = u << 16; b.i = u & 0xffff0000u; lo = a.f; hi = b.f;
}
__device__ __forceinline__ float gelu_exact(float x) {
  return 0.5f * x * (1.0f + erff(x * 0.70710678118654752f));
}
__device__ __forceinline__ float dot8(const uint4& u, const float* x, int k0) {
  float lo, hi, acc = 0.f;
  bfp(u.x, lo, hi); acc += x[k0  ]*lo + x[k0+1]*hi;
  bfp(u.y, lo, hi); acc += x[k0+2]*lo + x[k0+3]*hi;
  bfp(u.z, lo, hi); acc += x[k0+4]*lo + x[k0+5]*hi;
  bfp(u.w, lo, hi); acc += x[k0+6]*lo + x[k0+7]*hi;
  return acc;
}

// ---------------- weight fp32 -> bf16 ----------------
__global__ void convert_bf16(const float* qkv, const float* ow, const float* f1,
                             const float* f2, const float* w1, unsigned char* ws) {
  __hip_bfloat16* dst = (__hip_bfloat16*)(ws + WB_OFF);
  size_t stride = (size_t)gridDim.x * blockDim.x;
  for (size_t i = (size_t)blockIdx.x * blockDim.x + threadIdx.x; i < NCVT; i += stride) {
    float v;
    if      (i < WOFF_WO)  v = qkv[i];
    else if (i < WOFF_F1)  v = ow[i - WOFF_WO];
    else if (i < WOFF_F2)  v = f1[i - WOFF_F1];
    else if (i < WOFF_OP1) v = f2[i - WOFF_F2];
    else                   v = w1[i - WOFF_OP1];
    dst[i] = __float2bfloat16(v);
  }
}

// ---------------- one-shot per-(g,l): memvec chain + cross-attn const ----------------
__global__ void precompute_ca(const float* zs, const float* zk,
                              const float* mw1, const float* mb1,
                              const float* mlg, const float* mlb,
                              const float* mw2, const float* mb2,
                              const float* cqw, const float* cqb,
                              const float* cow, const float* cob,
                              unsigned char* ws) {
  const int g = blockIdx.x & 15, l = blockIdx.x >> 4;
  const int tid = threadIdx.x;           // 256 threads
  __shared__ float cond[128], h[256], mvv[256], vv[256], lred[16];

  auto lnstat = [&](float v, float& m, float& rs) {
    float a = v, b = v * v;
    #pragma unroll
    for (int off = 32; off; off >>= 1) { a += __shfl_xor(a, off); b += __shfl_xor(b, off); }
    if ((tid & 63) == 0) { lred[tid >> 6] = a; lred[4 + (tid >> 6)] = b; }
    __syncthreads();
    float sa = lred[0]+lred[1]+lred[2]+lred[3];
    float sb = lred[4]+lred[5]+lred[6]+lred[7];
    m = sa * (1.0f/256.0f);
    rs = rsqrtf(sb * (1.0f/256.0f) - m*m + 1e-5f);
    __syncthreads();
  };

  if (tid < 128) cond[tid] = (tid < 64) ? zs[g*64 + tid] : zk[g*64 + tid - 64];
  __syncthreads();
  float acc = mb1[tid];
  { const float* w = mw1 + (size_t)tid * 128;
    for (int k = 0; k < 128; k += 4) {
      float4 q = *(const float4*)(w + k);
      acc += q.x*cond[k] + q.y*cond[k+1] + q.z*cond[k+2] + q.w*cond[k+3];
    } }
  float m, rs; lnstat(acc, m, rs);
  h[tid] = gelu_exact((acc - m) * rs * mlg[tid] + mlb[tid]);
  __syncthreads();
  float a2 = mb2[tid];
  { const float* w = mw2 + (size_t)tid * 256;
    for (int k = 0; k < 256; k += 4) {
      float4 q = *(const float4*)(w + k);
      a2 += q.x*h[k] + q.y*h[k+1] + q.z*h[k+2] + q.w*h[k+3];
    } }
  mvv[tid] = a2;
  __syncthreads();
  float a3 = cqb[l*768 + 512 + tid];
  { const float* w = cqw + ((size_t)l*768 + 512 + tid) * 256;
    for (int k = 0; k < 256; k += 4) {
      float4 q = *(const float4*)(w + k);
      a3 += q.x*mvv[k] + q.y*mvv[k+1] + q.z*mvv[k+2] + q.w*mvv[k+3];
    } }
  vv[tid] = a3;
  __syncthreads();
  float a4 = cob[l*256 + tid];
  { const float* w = cow + ((size_t)l*256 + tid) * 256;
    for (int k = 0; k < 256; k += 4) {
      float4 q = *(const float4*)(w + k);
      a4 += q.x*vv[k] + q.y*vv[k+1] + q.z*vv[k+2] + q.w*vv[k+3];
    } }
  ((float*)(ws + GRP_OFF))[(size_t)g * GRP_STRF + CAL_F + l*256 + tid] = a4;
}

struct DecP {
  const float *start_token, *emb_w, *emb_b;
  const float *sa_qkv_b, *sa_o_b;
  const float *ln1_g, *ln1_b, *ln2_g, *ln2_b, *ln3_g, *ln3_b;
  const float *ff1_b, *ff2_b;
  const float *op_b1, *op_w2, *op_b2;
  float* out;
  unsigned char* ws;
};

// Persistent decoder: R17 base (1966us) + register-direct ff2 tile (stage_ff2
// deleted; forced-issue loads hide under LN+ff1) + stage_qkv moved earlier
// (issued at ff1-reads-done sync, drained by B2). -1 sync/Phase F.
__global__ __launch_bounds__(NTHR, 1) void decoder_persistent(DecP p) {
  const int g = blockIdx.x % NGRP;
  const int s = blockIdx.x / NGRP;     // head / ff-slice id 0..7
  const int tid = threadIdx.x;

  unsigned int* flg = (unsigned int*)(p.ws + CNT_OFF) + (size_t)g * 256;  // 8 slots x 128B
  float* grp = (float*)(p.ws + GRP_OFF) + (size_t)g * GRP_STRF;
  float* Po = grp + PO_F;
  float* Pf = grp + PF_F;
  const float* CALW = grp + CAL_F;
  const unsigned short* WB = (const unsigned short*)(p.ws + WB_OFF);

  __shared__ __align__(16) unsigned short Rws[32768];   // 64KB weight stage region
  __shared__ float xls[DDIM], x2ls[DDIM], lred[32], fxl[128];
  __shared__ float qb[HDIM], ah[HDIM], sc[64];
  __shared__ float kc[NLAY*TSEQ*33], vc[NLAY*TSEQ*33];   // padded stride 33
  __shared__ float cals[768], obias[768], ff2b[768];
  __shared__ float ln1g[768], ln1b[768], ln2g[768], ln2b[768], ln3g[768], ln3b[768];
  __shared__ float qkvb[288], ff1b[384];
  __shared__ float embw[DDIM*NOUT], embb[DDIM];
  __shared__ float opb1[128], opw2[NOUT*128], opb2[8], OUTV[8];

  const int row = tid >> 2, kk = tid & 3;    // 4 threads per GEMV output row
  const int rw2 = tid >> 1, kh2 = tid & 1;   // pair-lane mapping (oproj/ff2)
  const int wv = tid >> 6, ln = tid & 63;    // wave id / lane id

  // ---- weight staging (async DMA; swizzled source gather, linear LDS dest) ----
  auto stage_qkv = [&](int l) {     // 96 rows x 512B, 8-slot swizzle
    #pragma unroll
    for (int r = 0; r < 6; ++r) {
      int c = (r*8 + wv)*64 + ln;
      int rw = c >> 5, wc = (c & 31) ^ (rw & 7);
      const unsigned short* gp = WB + WOFF_QKV
        + ((size_t)(l*768 + (rw>>5)*256 + s*32 + (rw&31)))*256 + wc*8;
      gl_lds16(gp, Rws + (size_t)(r*8 + wv)*512);
    }
  };
  auto stage_ff1 = [&](int l) {     // 128 rows x 512B, 8-slot swizzle
    #pragma unroll
    for (int r = 0; r < 8; ++r) {
      int c = (r*8 + wv)*64 + ln;
      int rw = c >> 5, wc = (c & 31) ^ (rw & 7);
      const unsigned short* gp = WB + WOFF_F1
        + ((size_t)(l*1024 + s*128 + rw))*256 + wc*8;
      gl_lds16(gp, Rws + (size_t)(r*8 + wv)*512);
    }
  };

  // ---- small register tiles ----
  uint4 pWO[2], pO1[8];
  auto ldWO = [&](int l) {         // o-proj row rw2, k-half kh2 of own head (pair-lane)
    const unsigned short* w = WB + WOFF_WO + ((size_t)(l*256 + rw2))*256 + s*32 + kh2*16;
    pWO[0] = *(const uint4*)(w);
    pWO[1] = *(const uint4*)(w + 8);
  };
  auto ldO1 = [&]() {              // op_w1 rows (row, kk quarter)
    const unsigned short* w = WB + WOFF_OP1 + (size_t)row*256 + kk*64;
    #pragma unroll
    for (int i = 0; i < 8; ++i) pO1[i] = *(const uint4*)(w + i*8);
  };

  // ---- flag-vector barrier (R6-proven; no stager inside) ----
  unsigned int barcount = 0;
  auto gbar = [&]() {
    __syncthreads();
    ++barcount;
    if (tid == 0)
      __hip_atomic_store(flg + s*32, barcount, __ATOMIC_RELEASE, __HIP_MEMORY_SCOPE_AGENT);
    if (tid < GWG) {
      while (__hip_atomic_load(flg + tid*32, __ATOMIC_RELAXED, __HIP_MEMORY_SCOPE_AGENT) < barcount) {}
    }
    if (tid == 0)
      (void)__hip_atomic_load(flg + s*32, __ATOMIC_ACQUIRE, __HIP_MEMORY_SCOPE_AGENT);
    __syncthreads();
  };

  // ---- single-sync LN stats, per-site slots ----
  auto lnstats = [&](float v, float* slot, float& m, float& rs) {
    float a = v, b = v * v;
    #pragma unroll
    for (int off = 32; off; off >>= 1) { a += __shfl_xor(a, off); b += __shfl_xor(b, off); }
    if ((tid & 63) == 0 && tid < 256) { slot[tid >> 6] = a; slot[4 + (tid >> 6)] = b; }
    __syncthreads();
    float sa = slot[0]+slot[1]+slot[2]+slot[3];
    float sb = slot[4]+slot[5]+slot[6]+slot[7];
    m = sa * (1.0f/256.0f);
    rs = rsqrtf(sb * (1.0f/256.0f) - m*m + 1e-5f);
  };

  // ---- small params -> LDS ----
  for (int i = tid; i < 768; i += NTHR) {
    cals[i]  = CALW[i];
    obias[i] = p.sa_o_b[i];
    ff2b[i]  = p.ff2_b[i];
    ln1g[i] = p.ln1_g[i]; ln1b[i] = p.ln1_b[i];
    ln2g[i] = p.ln2_g[i]; ln2b[i] = p.ln2_b[i];
    ln3g[i] = p.ln3_g[i]; ln3b[i] = p.ln3_b[i];
  }
  for (int i = tid; i < 288; i += NTHR) {
    int l = i / 96, r = i % 96, sect = (r >> 5), o = r & 31;
    qkvb[i] = p.sa_qkv_b[l*768 + sect*256 + s*32 + o];
  }
  for (int i = tid; i < 384; i += NTHR) {
    int l = i >> 7, o = i & 127;
    ff1b[i] = p.ff1_b[l*1024 + s*128 + o];
  }
  for (int i = tid; i < DDIM*NOUT; i += NTHR) embw[i] = p.emb_w[i];
  for (int i = tid; i < DDIM; i += NTHR) embb[i] = p.emb_b[i];
  for (int i = tid; i < 128; i += NTHR) opb1[i] = p.op_b1[i];
  for (int i = tid; i < NOUT*128; i += NTHR) opw2[i] = p.op_w2[i];
  if (tid < NOUT) OUTV[tid] = p.start_token[tid];
  if (tid < 8) opb2[tid] = (tid < NOUT) ? p.op_b2[tid] : 0.f;

  const float divv = (tid < 256) ? expf(-0.035977892078031968f * (float)(2*(tid>>1))) : 0.f;
  __syncthreads();

  // prologue: x(t=0) + stage qkv(0) + WO(0)
  if (tid < 256) {
    float acc = embb[tid] + ((tid & 1) ? 1.0f : 0.0f);   // pe(t=0): sin0=0, cos0=1
    #pragma unroll
    for (int j = 0; j < NOUT; ++j) acc += OUTV[j] * embw[tid*NOUT + j];
    xls[tid] = acc;
  }
  stage_qkv(0);
  ldWO(0);
  __syncthreads();   // drains DMA + xls

  for (int t = 0; t < TSEQ; ++t) {
    for (int l = 0; l < NLAY; ++l) {
      // ================= PHASE Q =================
      if (l > 0) {
        float r2 = 0.f;
        if (tid < 256) {
          r2 = x2ls[tid] + ff2b[(l-1)*256 + tid];
          #pragma unroll
          for (int ss = 0; ss < GWG; ++ss) r2 += Pf[ss*256 + tid];
        }
        float m, rs; lnstats(r2, lred + 0, m, rs);
        if (tid < 256)
          xls[tid] = (r2 - m) * rs * ln3g[(l-1)*256 + tid] + ln3b[(l-1)*256 + tid];
        __syncthreads();
      }
      // qkv GEMV (staged LDS, 4 lanes/row, shuffle reduce)
      if (row < 96) {
        float acc = 0.f;
        #pragma unroll
        for (int i = 0; i < 8; ++i) {
          int ii = (i + kk) & 7;
          int k0 = kk*64 + ii*8;
          const uint4 w = *(const uint4*)(Rws + row*256 + (k0 ^ ((row&7)<<3)));
          acc += dot8(w, xls, k0);
        }
        acc += __shfl_xor(acc, 1);
        acc += __shfl_xor(acc, 2);
        if (kk == 0) {
          float v = acc + qkvb[l*96 + row];
          int sect = row >> 5, o = row & 31;
          if (sect == 0) qb[o] = v;
          else if (sect == 1) kc[(l*TSEQ + t)*33 + o] = v;
          else vc[(l*TSEQ + t)*33 + o] = v;
        }
      }
      __syncthreads();           // qkv Rws reads done; qb/kc/vc visible
      stage_ff1(l);              // async; drains by the post-attention sync
      // attention fully in wave 0: scores + softmax + PV (in-wave DS handoff)
      if (tid < 64) {
        float scj = -1e30f;
        if (tid <= t) {
          const float* kr = &kc[(l*TSEQ + tid)*33];
          float a = 0.f;
          #pragma unroll
          for (int d = 0; d < HDIM; ++d) a += qb[d] * kr[d];
          scj = a * 0.17677669529663687f;
        }
        float mx = scj;
        #pragma unroll
        for (int off = 32; off; off >>= 1) mx = fmaxf(mx, __shfl_xor(mx, off));
        float e = (tid <= t) ? expf(scj - mx) : 0.f;
        float su = e;
        #pragma unroll
        for (int off = 32; off; off >>= 1) su += __shfl_xor(su, off);
        sc[tid] = e / su;        // in-wave DS write; ordered vs reads below
        __builtin_amdgcn_wave_barrier();   // compiler fence (no reordering)
        // PV: 2 lanes per d (d = tid>>1, jg = tid&1), shuffle combine
        int d = tid >> 1, jg = tid & 1;
        float acc = 0.f;
        for (int j = jg; j <= t; j += 2) acc += sc[j] * vc[(l*TSEQ + j)*33 + d];
        acc += __shfl_xor(acc, 1);
        if (jg == 0) ah[d] = acc;
      }
      __syncthreads();           // ah visible to all; stage_ff1 DMA drained
      // oproj: pair-lane (row rw2, k-half kh2), shuffle combine -> Po direct
      {
        float acc = dot8(pWO[0], ah, kh2*16) + dot8(pWO[1], ah, kh2*16 + 8);
        acc += __shfl_xor(acc, 1);
        if (kh2 == 0) Po[s*256 + rw2] = acc;
      }
      gbar();   // B1

      // ================= PHASE F =================
      // register-direct ff2 tile (pair-lane); forced issue so the loads hide
      // under the LN+ff1 section instead of being sunk to their use (R5 lesson)
      uint4 pF2[8];
      {
        const unsigned short* w = WB + WOFF_F2 + ((size_t)(l*256 + rw2))*1024 + s*128 + kh2*64;
        #pragma unroll
        for (int i = 0; i < 8; ++i) pF2[i] = *(const uint4*)(w + i*8);
        #pragma unroll
        for (int i = 0; i < 8; ++i)
          asm volatile("" : "+v"(pF2[i].x), "+v"(pF2[i].y), "+v"(pF2[i].z), "+v"(pF2[i].w));
      }
      float r = 0.f;
      if (tid < 256) {
        r = xls[tid] + obias[l*256 + tid];
        #pragma unroll
        for (int ss = 0; ss < GWG; ++ss) r += Po[ss*256 + tid];
      }
      float m1, rs1; lnstats(r, lred + 8, m1, rs1);
      float z = 0.f;
      if (tid < 256)
        z = (r - m1)*rs1*ln1g[l*256 + tid] + ln1b[l*256 + tid] + cals[l*256 + tid];
      float m2, rs2; lnstats(z, lred + 16, m2, rs2);
      if (tid < 256) x2ls[tid] = (z - m2)*rs2*ln2g[l*256 + tid] + ln2b[l*256 + tid];
      __syncthreads();
      // ff1 GEMV (staged LDS, 4 lanes/row, shuffle reduce)
      float facc = 0.f;
      {
        #pragma unroll
        for (int i = 0; i < 8; ++i) {
          int ii = (i + kk) & 7;
          int k0 = kk*64 + ii*8;
          const uint4 w = *(const uint4*)(Rws + row*256 + (k0 ^ ((row&7)<<3)));
          facc += dot8(w, x2ls, k0);
        }
        facc += __shfl_xor(facc, 1);
        facc += __shfl_xor(facc, 2);
      }
      __syncthreads();             // all ff1 Rws reads done -> Rws free
      {
        int lnx = (l == 2) ? 0 : l + 1;
        stage_qkv(lnx);            // async; drains across B2 (long shadow now)
        ldWO(lnx);
        if (l == 2) ldO1();
      }
      if (kk == 0) fxl[row] = gelu_exact(facc + ff1b[l*128 + row]);
      __syncthreads();             // fxl visible
      // ff2: pair-lane from REGISTERS -> Pf direct (no LDS, no extra sync)
      {
        float acc = 0.f;
        #pragma unroll
        for (int j = 0; j < 8; ++j) acc += dot8(pF2[j], fxl, kh2*64 + j*8);
        acc += __shfl_xor(acc, 1);
        if (kh2 == 0) Pf[s*256 + rw2] = acc;
      }
      gbar();   // B2 (qkv DMA drained by barrier syncs)
    } // l

    // ============ STEP TAIL: ln3(l2) + output head + next-step x, all WGs ========
    {
      float r2 = 0.f;
      if (tid < 256) {
        r2 = x2ls[tid] + ff2b[2*256 + tid];
        #pragma unroll
        for (int ss = 0; ss < GWG; ++ss) r2 += Pf[ss*256 + tid];
      }
      float m, rs; lnstats(r2, lred + 24, m, rs);
      if (tid < 256) xls[tid] = (r2 - m)*rs*ln3g[2*256 + tid] + ln3b[2*256 + tid];
      __syncthreads();
      // op1 (register tile, 4 lanes/row, shuffle reduce)
      float oacc = 0.f;
      #pragma unroll
      for (int i = 0; i < 8; ++i) oacc += dot8(pO1[i], xls, kk*64 + i*8);
      oacc += __shfl_xor(oacc, 1);
      oacc += __shfl_xor(oacc, 2);
      if (kk == 0) fxl[row] = gelu_exact(oacc + opb1[row]);
      __syncthreads();
      // op2
      if (tid < 192) {
        int oo = tid >> 5, kl = tid & 31;
        float acc = fxl[kl]*opw2[oo*128 + kl] + fxl[kl+32]*opw2[oo*128 + kl+32]
                  + fxl[kl+64]*opw2[oo*128 + kl+64] + fxl[kl+96]*opw2[oo*128 + kl+96];
        #pragma unroll
        for (int off = 16; off; off >>= 1) acc += __shfl_xor(acc, off);
        if (kl == 0) {
          float v = acc + opb2[oo];
          OUTV[oo] = v;
          if (s == 0) p.out[((size_t)g*TSEQ + t)*NOUT + oo] = v;
        }
      }
      __syncthreads();
      // next-step x build (harmless at t=47)
      if (tid < 256) {
        float ang = (float)(t + 1) * divv;
        float pe = (tid & 1) ? cosf(ang) : sinf(ang);
        float acc = embb[tid] + pe;
        #pragma unroll
        for (int j = 0; j < NOUT; ++j) acc += OUTV[j] * embw[tid*NOUT + j];
        xls[tid] = acc;
      }
      __syncthreads();
    }
  } // t
}

extern "C" void kernel_launch(void* const* d_in, const int* in_sizes, int n_in,
                              void* d_out, int out_size, void* d_ws, size_t ws_size,
                              hipStream_t stream) {
  const float* const* F = (const float* const*)d_in;
  const float* z_style = F[0]; const float* z_skill = F[1];
  DecP p;
  p.start_token = F[2];
  const float* mem_w1 = F[3]; const float* mem_b1 = F[4];
  const float* mem_ln_g = F[5]; const float* mem_ln_b = F[6];
  const float* mem_w2 = F[7]; const float* mem_b2 = F[8];
  p.emb_w = F[9]; p.emb_b = F[10];
  const float* sa_qkv_w = F[11]; p.sa_qkv_b = F[12];
  const float* sa_o_w  = F[13]; p.sa_o_b = F[14];
  const float* ca_qkv_w = F[15]; const float* ca_qkv_b = F[16];
  const float* ca_o_w = F[17]; const float* ca_o_b = F[18];
  p.ln1_g = F[19]; p.ln1_b = F[20]; p.ln2_g = F[21]; p.ln2_b = F[22];
  p.ln3_g = F[23]; p.ln3_b = F[24];
  const float* ff1_w = F[25]; p.ff1_b = F[26];
  const float* ff2_w = F[27]; p.ff2_b = F[28];
  const float* op_w1 = F[29]; p.op_b1 = F[30]; p.op_w2 = F[31]; p.op_b2 = F[32];
  p.out = (float*)d_out;
  p.ws  = (unsigned char*)d_ws;

  hipMemsetAsync((char*)d_ws + CNT_OFF, 0, CNT_BYTES, stream);
  convert_bf16<<<dim3(512), dim3(256), 0, stream>>>(sa_qkv_w, sa_o_w, ff1_w, ff2_w, op_w1,
                                                    (unsigned char*)d_ws);
  precompute_ca<<<dim3(48), dim3(256), 0, stream>>>(z_style, z_skill, mem_w1, mem_b1,
                                                    mem_ln_g, mem_ln_b, mem_w2, mem_b2,
                                                    ca_qkv_w, ca_qkv_b, ca_o_w, ca_o_b,
                                                    (unsigned char*)d_ws);
  decoder_persistent<<<dim3(NBLK), dim3(NTHR), 0, stream>>>(p);
}

// Round 21
// 1981.372 us; speedup vs baseline: 1.0955x; 1.0955x over previous
//
#include <hip/hip_runtime.h>
#include <hip/hip_bf16.h>
#include <math.h>

// ---------------- problem constants ----------------
#define NGRP 16     // batch groups (one per batch element)
#define GWG  8      // workgroups per group (= heads)
#define NBLK (NGRP*GWG)   // 128
#define NTHR 512
#define TSEQ 48
#define DDIM 256
#define HDIM 32
#define NLAY 3
#define NOUT 6

// ---------------- ws layout ----------------
#define CNT_OFF   0u
#define CNT_BYTES 16384u         // 16 groups x 8 flag slots x 128B
#define GRP_OFF   16384u
#define GRP_STRF  5120u          // floats per group block
#define PO_F   0                 // [8*256] oproj partials
#define PF_F   2048              // [8*256] ff2 partials
#define CAL_F  4096              // [3*256] cross-attn constants
#define WB_OFF 360448u           // bf16 weights (element offsets below)
#define WOFF_QKV 0u
#define WOFF_WO  589824u
#define WOFF_F1  786432u
#define WOFF_F2  1572864u
#define WOFF_OP1 2359296u
#define NCVT     2392064u

typedef __attribute__((address_space(1))) const unsigned int gu32;
typedef __attribute__((address_space(3))) unsigned int lu32;

__device__ __forceinline__ void gl_lds16(const unsigned short* g, unsigned short* l) {
  __builtin_amdgcn_global_load_lds((gu32*)g, (lu32*)l, 16, 0, 0);
}
__device__ __forceinline__ void bfp(unsigned int u, float& lo, float& hi) {
  union { unsigned int i; float f; } a, b;
  a.i = u << 16; b.i = u & 0xffff0000u; lo = a.f; hi = b.f;
}
__device__ __forceinline__ float gelu_exact(float x) {
  return 0.5f * x * (1.0f + erff(x * 0.70710678118654752f));
}
__device__ __forceinline__ float dot8(const uint4& u, const float* x, int k0) {
  float lo, hi, acc = 0.f;
  bfp(u.x, lo, hi); acc += x[k0  ]*lo + x[k0+1]*hi;
  bfp(u.y, lo, hi); acc += x[k0+2]*lo + x[k0+3]*hi;
  bfp(u.z, lo, hi); acc += x[k0+4]*lo + x[k0+5]*hi;
  bfp(u.w, lo, hi); acc += x[k0+6]*lo + x[k0+7]*hi;
  return acc;
}

// ---------------- weight fp32 -> bf16 ----------------
__global__ void convert_bf16(const float* qkv, const float* ow, const float* f1,
                             const float* f2, const float* w1, unsigned char* ws) {
  __hip_bfloat16* dst = (__hip_bfloat16*)(ws + WB_OFF);
  size_t stride = (size_t)gridDim.x * blockDim.x;
  for (size_t i = (size_t)blockIdx.x * blockDim.x + threadIdx.x; i < NCVT; i += stride) {
    float v;
    if      (i < WOFF_WO)  v = qkv[i];
    else if (i < WOFF_F1)  v = ow[i - WOFF_WO];
    else if (i < WOFF_F2)  v = f1[i - WOFF_F1];
    else if (i < WOFF_OP1) v = f2[i - WOFF_F2];
    else                   v = w1[i - WOFF_OP1];
    dst[i] = __float2bfloat16(v);
  }
}

// ---------------- one-shot per-(g,l): memvec chain + cross-attn const ----------------
__global__ void precompute_ca(const float* zs, const float* zk,
                              const float* mw1, const float* mb1,
                              const float* mlg, const float* mlb,
                              const float* mw2, const float* mb2,
                              const float* cqw, const float* cqb,
                              const float* cow, const float* cob,
                              unsigned char* ws) {
  const int g = blockIdx.x & 15, l = blockIdx.x >> 4;
  const int tid = threadIdx.x;           // 256 threads
  __shared__ float cond[128], h[256], mvv[256], vv[256], lred[16];

  auto lnstat = [&](float v, float& m, float& rs) {
    float a = v, b = v * v;
    #pragma unroll
    for (int off = 32; off; off >>= 1) { a += __shfl_xor(a, off); b += __shfl_xor(b, off); }
    if ((tid & 63) == 0) { lred[tid >> 6] = a; lred[4 + (tid >> 6)] = b; }
    __syncthreads();
    float sa = lred[0]+lred[1]+lred[2]+lred[3];
    float sb = lred[4]+lred[5]+lred[6]+lred[7];
    m = sa * (1.0f/256.0f);
    rs = rsqrtf(sb * (1.0f/256.0f) - m*m + 1e-5f);
    __syncthreads();
  };

  if (tid < 128) cond[tid] = (tid < 64) ? zs[g*64 + tid] : zk[g*64 + tid - 64];
  __syncthreads();
  float acc = mb1[tid];
  { const float* w = mw1 + (size_t)tid * 128;
    for (int k = 0; k < 128; k += 4) {
      float4 q = *(const float4*)(w + k);
      acc += q.x*cond[k] + q.y*cond[k+1] + q.z*cond[k+2] + q.w*cond[k+3];
    } }
  float m, rs; lnstat(acc, m, rs);
  h[tid] = gelu_exact((acc - m) * rs * mlg[tid] + mlb[tid]);
  __syncthreads();
  float a2 = mb2[tid];
  { const float* w = mw2 + (size_t)tid * 256;
    for (int k = 0; k < 256; k += 4) {
      float4 q = *(const float4*)(w + k);
      a2 += q.x*h[k] + q.y*h[k+1] + q.z*h[k+2] + q.w*h[k+3];
    } }
  mvv[tid] = a2;
  __syncthreads();
  float a3 = cqb[l*768 + 512 + tid];
  { const float* w = cqw + ((size_t)l*768 + 512 + tid) * 256;
    for (int k = 0; k < 256; k += 4) {
      float4 q = *(const float4*)(w + k);
      a3 += q.x*mvv[k] + q.y*mvv[k+1] + q.z*mvv[k+2] + q.w*mvv[k+3];
    } }
  vv[tid] = a3;
  __syncthreads();
  float a4 = cob[l*256 + tid];
  { const float* w = cow + ((size_t)l*256 + tid) * 256;
    for (int k = 0; k < 256; k += 4) {
      float4 q = *(const float4*)(w + k);
      a4 += q.x*vv[k] + q.y*vv[k+1] + q.z*vv[k+2] + q.w*vv[k+3];
    } }
  ((float*)(ws + GRP_OFF))[(size_t)g * GRP_STRF + CAL_F + l*256 + tid] = a4;
}

struct DecP {
  const float *start_token, *emb_w, *emb_b;
  const float *sa_qkv_b, *sa_o_b;
  const float *ln1_g, *ln1_b, *ln2_g, *ln2_b, *ln3_g, *ln3_b;
  const float *ff1_b, *ff2_b;
  const float *op_b1, *op_w2, *op_b2;
  float* out;
  unsigned char* ws;
};

// Persistent decoder (FINAL = R17, best verified 1966us, reproduced 3x):
// 16 groups x 8 WGs x 512 threads; flag-vector group barrier (R6); LDS weight
// staging via global_load_lds with XOR-swizzle (R7); shuffle-reduce GEMVs +
// single-sync LN + fused tail (R10); wave0-contained attention + pair-lane
// oproj/ff2 (R17). Latency/sync-bound floor: 6 all-to-all exchanges/step.
__global__ __launch_bounds__(NTHR, 1) void decoder_persistent(DecP p) {
  const int g = blockIdx.x % NGRP;
  const int s = blockIdx.x / NGRP;     // head / ff-slice id 0..7
  const int tid = threadIdx.x;

  unsigned int* flg = (unsigned int*)(p.ws + CNT_OFF) + (size_t)g * 256;  // 8 slots x 128B
  float* grp = (float*)(p.ws + GRP_OFF) + (size_t)g * GRP_STRF;
  float* Po = grp + PO_F;
  float* Pf = grp + PF_F;
  const float* CALW = grp + CAL_F;
  const unsigned short* WB = (const unsigned short*)(p.ws + WB_OFF);

  __shared__ __align__(16) unsigned short Rws[32768];   // 64KB weight stage region
  __shared__ float xls[DDIM], x2ls[DDIM], lred[32], fxl[128];
  __shared__ float qb[HDIM], ah[HDIM], sc[64];
  __shared__ float kc[NLAY*TSEQ*33], vc[NLAY*TSEQ*33];   // padded stride 33
  __shared__ float cals[768], obias[768], ff2b[768];
  __shared__ float ln1g[768], ln1b[768], ln2g[768], ln2b[768], ln3g[768], ln3b[768];
  __shared__ float qkvb[288], ff1b[384];
  __shared__ float embw[DDIM*NOUT], embb[DDIM];
  __shared__ float opb1[128], opw2[NOUT*128], opb2[8], OUTV[8];

  const int row = tid >> 2, kk = tid & 3;    // 4 threads per GEMV output row
  const int rw2 = tid >> 1, kh2 = tid & 1;   // pair-lane mapping (oproj/ff2)
  const int wv = tid >> 6, ln = tid & 63;    // wave id / lane id

  // ---- weight staging (async DMA; swizzled source gather, linear LDS dest) ----
  auto stage_qkv = [&](int l) {     // 96 rows x 512B, 8-slot swizzle
    #pragma unroll
    for (int r = 0; r < 6; ++r) {
      int c = (r*8 + wv)*64 + ln;
      int rw = c >> 5, wc = (c & 31) ^ (rw & 7);
      const unsigned short* gp = WB + WOFF_QKV
        + ((size_t)(l*768 + (rw>>5)*256 + s*32 + (rw&31)))*256 + wc*8;
      gl_lds16(gp, Rws + (size_t)(r*8 + wv)*512);
    }
  };
  auto stage_ff1 = [&](int l) {     // 128 rows x 512B, 8-slot swizzle
    #pragma unroll
    for (int r = 0; r < 8; ++r) {
      int c = (r*8 + wv)*64 + ln;
      int rw = c >> 5, wc = (c & 31) ^ (rw & 7);
      const unsigned short* gp = WB + WOFF_F1
        + ((size_t)(l*1024 + s*128 + rw))*256 + wc*8;
      gl_lds16(gp, Rws + (size_t)(r*8 + wv)*512);
    }
  };
  auto stage_ff2 = [&](int l) {     // 256 rows x 256B, 16-slot swizzle
    #pragma unroll
    for (int r = 0; r < 8; ++r) {
      int c = (r*8 + wv)*64 + ln;
      int rw = c >> 4, wc = (c & 15) ^ (rw & 15);
      const unsigned short* gp = WB + WOFF_F2
        + ((size_t)(l*256 + rw))*1024 + s*128 + wc*8;
      gl_lds16(gp, Rws + (size_t)(r*8 + wv)*512);
    }
  };

  // ---- small register tiles ----
  uint4 pWO[2], pO1[8];
  auto ldWO = [&](int l) {         // o-proj row rw2, k-half kh2 of own head (pair-lane)
    const unsigned short* w = WB + WOFF_WO + ((size_t)(l*256 + rw2))*256 + s*32 + kh2*16;
    pWO[0] = *(const uint4*)(w);
    pWO[1] = *(const uint4*)(w + 8);
  };
  auto ldO1 = [&]() {              // op_w1 rows (row, kk quarter)
    const unsigned short* w = WB + WOFF_OP1 + (size_t)row*256 + kk*64;
    #pragma unroll
    for (int i = 0; i < 8; ++i) pO1[i] = *(const uint4*)(w + i*8);
  };

  // ---- flag-vector barrier (R6-proven; no stager inside) ----
  unsigned int barcount = 0;
  auto gbar = [&]() {
    __syncthreads();
    ++barcount;
    if (tid == 0)
      __hip_atomic_store(flg + s*32, barcount, __ATOMIC_RELEASE, __HIP_MEMORY_SCOPE_AGENT);
    if (tid < GWG) {
      while (__hip_atomic_load(flg + tid*32, __ATOMIC_RELAXED, __HIP_MEMORY_SCOPE_AGENT) < barcount) {}
    }
    if (tid == 0)
      (void)__hip_atomic_load(flg + s*32, __ATOMIC_ACQUIRE, __HIP_MEMORY_SCOPE_AGENT);
    __syncthreads();
  };

  // ---- single-sync LN stats, per-site slots ----
  auto lnstats = [&](float v, float* slot, float& m, float& rs) {
    float a = v, b = v * v;
    #pragma unroll
    for (int off = 32; off; off >>= 1) { a += __shfl_xor(a, off); b += __shfl_xor(b, off); }
    if ((tid & 63) == 0 && tid < 256) { slot[tid >> 6] = a; slot[4 + (tid >> 6)] = b; }
    __syncthreads();
    float sa = slot[0]+slot[1]+slot[2]+slot[3];
    float sb = slot[4]+slot[5]+slot[6]+slot[7];
    m = sa * (1.0f/256.0f);
    rs = rsqrtf(sb * (1.0f/256.0f) - m*m + 1e-5f);
  };

  // ---- small params -> LDS ----
  for (int i = tid; i < 768; i += NTHR) {
    cals[i]  = CALW[i];
    obias[i] = p.sa_o_b[i];
    ff2b[i]  = p.ff2_b[i];
    ln1g[i] = p.ln1_g[i]; ln1b[i] = p.ln1_b[i];
    ln2g[i] = p.ln2_g[i]; ln2b[i] = p.ln2_b[i];
    ln3g[i] = p.ln3_g[i]; ln3b[i] = p.ln3_b[i];
  }
  for (int i = tid; i < 288; i += NTHR) {
    int l = i / 96, r = i % 96, sect = (r >> 5), o = r & 31;
    qkvb[i] = p.sa_qkv_b[l*768 + sect*256 + s*32 + o];
  }
  for (int i = tid; i < 384; i += NTHR) {
    int l = i >> 7, o = i & 127;
    ff1b[i] = p.ff1_b[l*1024 + s*128 + o];
  }
  for (int i = tid; i < DDIM*NOUT; i += NTHR) embw[i] = p.emb_w[i];
  for (int i = tid; i < DDIM; i += NTHR) embb[i] = p.emb_b[i];
  for (int i = tid; i < 128; i += NTHR) opb1[i] = p.op_b1[i];
  for (int i = tid; i < NOUT*128; i += NTHR) opw2[i] = p.op_w2[i];
  if (tid < NOUT) OUTV[tid] = p.start_token[tid];
  if (tid < 8) opb2[tid] = (tid < NOUT) ? p.op_b2[tid] : 0.f;

  const float divv = (tid < 256) ? expf(-0.035977892078031968f * (float)(2*(tid>>1))) : 0.f;
  __syncthreads();

  // prologue: x(t=0) + stage qkv(0) + WO(0)
  if (tid < 256) {
    float acc = embb[tid] + ((tid & 1) ? 1.0f : 0.0f);   // pe(t=0): sin0=0, cos0=1
    #pragma unroll
    for (int j = 0; j < NOUT; ++j) acc += OUTV[j] * embw[tid*NOUT + j];
    xls[tid] = acc;
  }
  stage_qkv(0);
  ldWO(0);
  __syncthreads();   // drains DMA + xls

  for (int t = 0; t < TSEQ; ++t) {
    for (int l = 0; l < NLAY; ++l) {
      // ================= PHASE Q =================
      if (l > 0) {
        float r2 = 0.f;
        if (tid < 256) {
          r2 = x2ls[tid] + ff2b[(l-1)*256 + tid];
          #pragma unroll
          for (int ss = 0; ss < GWG; ++ss) r2 += Pf[ss*256 + tid];
        }
        float m, rs; lnstats(r2, lred + 0, m, rs);
        if (tid < 256)
          xls[tid] = (r2 - m) * rs * ln3g[(l-1)*256 + tid] + ln3b[(l-1)*256 + tid];
        __syncthreads();
      }
      // qkv GEMV (staged LDS, 4 lanes/row, shuffle reduce)
      if (row < 96) {
        float acc = 0.f;
        #pragma unroll
        for (int i = 0; i < 8; ++i) {
          int ii = (i + kk) & 7;
          int k0 = kk*64 + ii*8;
          const uint4 w = *(const uint4*)(Rws + row*256 + (k0 ^ ((row&7)<<3)));
          acc += dot8(w, xls, k0);
        }
        acc += __shfl_xor(acc, 1);
        acc += __shfl_xor(acc, 2);
        if (kk == 0) {
          float v = acc + qkvb[l*96 + row];
          int sect = row >> 5, o = row & 31;
          if (sect == 0) qb[o] = v;
          else if (sect == 1) kc[(l*TSEQ + t)*33 + o] = v;
          else vc[(l*TSEQ + t)*33 + o] = v;
        }
      }
      __syncthreads();           // qkv Rws reads done; qb/kc/vc visible
      stage_ff1(l);              // async; drains by the post-attention sync
      // attention fully in wave 0: scores + softmax + PV (in-wave DS handoff)
      if (tid < 64) {
        float scj = -1e30f;
        if (tid <= t) {
          const float* kr = &kc[(l*TSEQ + tid)*33];
          float a = 0.f;
          #pragma unroll
          for (int d = 0; d < HDIM; ++d) a += qb[d] * kr[d];
          scj = a * 0.17677669529663687f;
        }
        float mx = scj;
        #pragma unroll
        for (int off = 32; off; off >>= 1) mx = fmaxf(mx, __shfl_xor(mx, off));
        float e = (tid <= t) ? expf(scj - mx) : 0.f;
        float su = e;
        #pragma unroll
        for (int off = 32; off; off >>= 1) su += __shfl_xor(su, off);
        sc[tid] = e / su;        // in-wave DS write; ordered vs reads below
        __builtin_amdgcn_wave_barrier();   // compiler fence (no reordering)
        // PV: 2 lanes per d (d = tid>>1, jg = tid&1), shuffle combine
        int d = tid >> 1, jg = tid & 1;
        float acc = 0.f;
        for (int j = jg; j <= t; j += 2) acc += sc[j] * vc[(l*TSEQ + j)*33 + d];
        acc += __shfl_xor(acc, 1);
        if (jg == 0) ah[d] = acc;
      }
      __syncthreads();           // ah visible to all; stage_ff1 DMA drained
      // oproj: pair-lane (row rw2, k-half kh2), shuffle combine -> Po direct
      {
        float acc = dot8(pWO[0], ah, kh2*16) + dot8(pWO[1], ah, kh2*16 + 8);
        acc += __shfl_xor(acc, 1);
        if (kh2 == 0) Po[s*256 + rw2] = acc;
      }
      gbar();   // B1

      // ================= PHASE F =================
      float r = 0.f;
      if (tid < 256) {
        r = xls[tid] + obias[l*256 + tid];
        #pragma unroll
        for (int ss = 0; ss < GWG; ++ss) r += Po[ss*256 + tid];
      }
      float m1, rs1; lnstats(r, lred + 8, m1, rs1);
      float z = 0.f;
      if (tid < 256)
        z = (r - m1)*rs1*ln1g[l*256 + tid] + ln1b[l*256 + tid] + cals[l*256 + tid];
      float m2, rs2; lnstats(z, lred + 16, m2, rs2);
      if (tid < 256) x2ls[tid] = (z - m2)*rs2*ln2g[l*256 + tid] + ln2b[l*256 + tid];
      __syncthreads();
      // ff1 GEMV (staged LDS, 4 lanes/row, shuffle reduce)
      float facc = 0.f;
      {
        #pragma unroll
        for (int i = 0; i < 8; ++i) {
          int ii = (i + kk) & 7;
          int k0 = kk*64 + ii*8;
          const uint4 w = *(const uint4*)(Rws + row*256 + (k0 ^ ((row&7)<<3)));
          facc += dot8(w, x2ls, k0);
        }
        facc += __shfl_xor(facc, 1);
        facc += __shfl_xor(facc, 2);
      }
      __syncthreads();             // all ff1 Rws reads done
      stage_ff2(l);                // async; gelu overlaps part of it
      if (kk == 0) fxl[row] = gelu_exact(facc + ff1b[l*128 + row]);
      __syncthreads();             // drains ff2 DMA + fxl visible
      // ff2: pair-lane (row rw2, k-half kh2), shuffle combine -> Pf direct
      {
        float acc = 0.f;
        #pragma unroll
        for (int j = 0; j < 8; ++j) {
          int k0 = kh2*64 + j*8;
          const uint4 w = *(const uint4*)(Rws + rw2*128 + (k0 ^ ((rw2&15)<<3)));
          acc += dot8(w, fxl, k0);
        }
        acc += __shfl_xor(acc, 1);
        if (kh2 == 0) Pf[s*256 + rw2] = acc;
      }
      __syncthreads();             // ff2 Rws reads done (before qkv DMA overwrites)
      {
        int lnx = (l == 2) ? 0 : l + 1;
        stage_qkv(lnx);            // async; drains across B2
        ldWO(lnx);
        if (l == 2) ldO1();
      }
      gbar();   // B2
    } // l

    // ============ STEP TAIL: ln3(l2) + output head + next-step x, all WGs ========
    {
      float r2 = 0.f;
      if (tid < 256) {
        r2 = x2ls[tid] + ff2b[2*256 + tid];
        #pragma unroll
        for (int ss = 0; ss < GWG; ++ss) r2 += Pf[ss*256 + tid];
      }
      float m, rs; lnstats(r2, lred + 24, m, rs);
      if (tid < 256) xls[tid] = (r2 - m)*rs*ln3g[2*256 + tid] + ln3b[2*256 + tid];
      __syncthreads();
      // op1 (register tile, 4 lanes/row, shuffle reduce)
      float oacc = 0.f;
      #pragma unroll
      for (int i = 0; i < 8; ++i) oacc += dot8(pO1[i], xls, kk*64 + i*8);
      oacc += __shfl_xor(oacc, 1);
      oacc += __shfl_xor(oacc, 2);
      if (kk == 0) fxl[row] = gelu_exact(oacc + opb1[row]);
      __syncthreads();
      // op2
      if (tid < 192) {
        int oo = tid >> 5, kl = tid & 31;
        float acc = fxl[kl]*opw2[oo*128 + kl] + fxl[kl+32]*opw2[oo*128 + kl+32]
                  + fxl[kl+64]*opw2[oo*128 + kl+64] + fxl[kl+96]*opw2[oo*128 + kl+96];
        #pragma unroll
        for (int off = 16; off; off >>= 1) acc += __shfl_xor(acc, off);
        if (kl == 0) {
          float v = acc + opb2[oo];
          OUTV[oo] = v;
          if (s == 0) p.out[((size_t)g*TSEQ + t)*NOUT + oo] = v;
        }
      }
      __syncthreads();
      // next-step x build (harmless at t=47)
      if (tid < 256) {
        float ang = (float)(t + 1) * divv;
        float pe = (tid & 1) ? cosf(ang) : sinf(ang);
        float acc = embb[tid] + pe;
        #pragma unroll
        for (int j = 0; j < NOUT; ++j) acc += OUTV[j] * embw[tid*NOUT + j];
        xls[tid] = acc;
      }
      __syncthreads();
    }
  } // t
}

extern "C" void kernel_launch(void* const* d_in, const int* in_sizes, int n_in,
                              void* d_out, int out_size, void* d_ws, size_t ws_size,
                              hipStream_t stream) {
  const float* const* F = (const float* const*)d_in;
  const float* z_style = F[0]; const float* z_skill = F[1];
  DecP p;
  p.start_token = F[2];
  const float* mem_w1 = F[3]; const float* mem_b1 = F[4];
  const float* mem_ln_g = F[5]; const float* mem_ln_b = F[6];
  const float* mem_w2 = F[7]; const float* mem_b2 = F[8];
  p.emb_w = F[9]; p.emb_b = F[10];
  const float* sa_qkv_w = F[11]; p.sa_qkv_b = F[12];
  const float* sa_o_w  = F[13]; p.sa_o_b = F[14];
  const float* ca_qkv_w = F[15]; const float* ca_qkv_b = F[16];
  const float* ca_o_w = F[17]; const float* ca_o_b = F[18];
  p.ln1_g = F[19]; p.ln1_b = F[20]; p.ln2_g = F[21]; p.ln2_b = F[22];
  p.ln3_g = F[23]; p.ln3_b = F[24];
  const float* ff1_w = F[25]; p.ff1_b = F[26];
  const float* ff2_w = F[27]; p.ff2_b = F[28];
  const float* op_w1 = F[29]; p.op_b1 = F[30]; p.op_w2 = F[31]; p.op_b2 = F[32];
  p.out = (float*)d_out;
  p.ws  = (unsigned char*)d_ws;

  hipMemsetAsync((char*)d_ws + CNT_OFF, 0, CNT_BYTES, stream);
  convert_bf16<<<dim3(512), dim3(256), 0, stream>>>(sa_qkv_w, sa_o_w, ff1_w, ff2_w, op_w1,
                                                    (unsigned char*)d_ws);
  precompute_ca<<<dim3(48), dim3(256), 0, stream>>>(z_style, z_skill, mem_w1, mem_b1,
                                                    mem_ln_g, mem_ln_b, mem_w2, mem_b2,
                                                    ca_qkv_w, ca_qkv_b, ca_o_w, ca_o_b,
                                                    (unsigned char*)d_ws);
  decoder_persistent<<<dim3(NBLK), dim3(NTHR), 0, stream>>>(p);
}